// Round 1
// baseline (166.365 us; speedup 1.0000x reference)
//
#include <hip/hip_runtime.h>
#include <hip/hip_bf16.h>
#include <math.h>

#define TOKS 16384
#define CDIM 1024
#define NEXP 8
#define RDIM 64
#define CAP  TOKS
#define NBLK_R 1024   // router blocks (16 tokens each)
#define DT_MAX 528    // max down tiles: 2*(16384/64 + 8)
#define UT_MAX 192    // max up tiles: 16384/128 + 64

using f32x4   = __attribute__((ext_vector_type(4))) float;
using bf16x8  = __attribute__((ext_vector_type(8))) short;
using ushort8 = __attribute__((ext_vector_type(8))) unsigned short;

__device__ __forceinline__ ushort f2bf(float f) {
  unsigned u = __builtin_bit_cast(unsigned, f);
  u += 0x7fffu + ((u >> 16) & 1u);   // round-to-nearest-even
  return (ushort)(u >> 16);
}

// ---- pre-pass: rw permute (router-coalesced), Wd->wdt[e][r][k], Wu->wut[e][c][r]
__global__ __launch_bounds__(256) void convert_kernel(
    const float* __restrict__ Wd, const float* __restrict__ Wu,
    const float* __restrict__ rw_all, const int* __restrict__ key_id,
    ushort* __restrict__ wdt, ushort* __restrict__ wut,
    float* __restrict__ rw_p) {
  const int t = blockIdx.x * 256 + threadIdx.x;
  if (t < 2048) {              // rw_p: one float4 per thread
    const int st = t >> 7, rem = t & 127;
    const int h = rem >> 6, l = rem & 63;
    const int C = (st >> 2) * 256 + l * 4 + (st & 3);
    const float4 v = *(const float4*)(rw_all + (size_t)key_id[0] * CDIM * NEXP
                                      + C * 8 + h * 4);
    ((float4*)rw_p)[t] = v;
  } else if (t < 133120) {     // Wd: (e, r, k4)
    const int u = t - 2048;
    const int k4 = u & 255, r = (u >> 8) & 63, e = u >> 14;
    ushort4 h;
    h.x = f2bf(Wd[(size_t)(e * 1024 + k4 * 4 + 0) * 64 + r]);
    h.y = f2bf(Wd[(size_t)(e * 1024 + k4 * 4 + 1) * 64 + r]);
    h.z = f2bf(Wd[(size_t)(e * 1024 + k4 * 4 + 2) * 64 + r]);
    h.w = f2bf(Wd[(size_t)(e * 1024 + k4 * 4 + 3) * 64 + r]);
    ((ushort4*)wdt)[(e * 64 + r) * 256 + k4] = h;
  } else {                     // Wu: (e, c, r4)
    const int u = t - 133120;
    const int r4 = u & 15, c = (u >> 4) & 1023, e = u >> 14;
    ushort4 h;
    h.x = f2bf(Wu[(size_t)(e * 64 + r4 * 4 + 0) * 1024 + c]);
    h.y = f2bf(Wu[(size_t)(e * 64 + r4 * 4 + 1) * 1024 + c]);
    h.z = f2bf(Wu[(size_t)(e * 64 + r4 * 4 + 2) * 1024 + c]);
    h.w = f2bf(Wu[(size_t)(e * 64 + r4 * 4 + 3) * 1024 + c]);
    ((ushort4*)wut)[(e * 1024 + c) * 16 + r4] = h;
  }
}

// ---------------- router: wave = token; NO global atomics ------------------
// Writes per-token records (pbuf/ggbuf) + transposed per-block histograms
// histT[c][blk] for 80 counters (16 (k,e) + 64 pairs). Slot assignment is
// deferred to scan_scatter_kernel (deterministic block-order prefix).
__global__ __launch_bounds__(256) void router_kernel(
    const float* __restrict__ x, const float* __restrict__ rw_p,
    const float* __restrict__ rb_all, const int* __restrict__ key_id,
    float* __restrict__ imp_part,
    int* __restrict__ pbuf, float2* __restrict__ ggbuf,
    int* __restrict__ histT, ushort* __restrict__ xb) {
  __shared__ float s_imp[4][NEXP];
  __shared__ int   s_e1[16], s_e2[16], s_pb[16];
  __shared__ float s_g1[16], s_g2[16];
  const int tid = threadIdx.x;
  const int lane = tid & 63;
  const int wave = tid >> 6;
  const int kid = key_id[0];
  const float4* rwp4 = (const float4*)rw_p;
  const float* rb = rb_all + (size_t)kid * NEXP;
  const int eln = ((lane & 1) << 2) | (lane & 2) | ((lane >> 2) & 1);
  const float rbe = rb[eln];
  float impacc = 0.f;

  const int wg = blockIdx.x * 4 + wave;
#pragma unroll 1
  for (int tt = 0; tt < 4; ++tt) {
    const int token = wg * 4 + tt;
    const float* xr = x + (size_t)token * CDIM + lane * 4;
    float4 xv[4];
#pragma unroll
    for (int j = 0; j < 4; ++j) xv[j] = *(const float4*)(xr + j * 256);
    ushort* xo = xb + (size_t)token * CDIM + lane * 4;
#pragma unroll
    for (int j = 0; j < 4; ++j) {
      ushort4 h;
      h.x = f2bf(xv[j].x); h.y = f2bf(xv[j].y);
      h.z = f2bf(xv[j].z); h.w = f2bf(xv[j].w);
      *(ushort4*)(xo + j * 256) = h;
    }
    float acc[8];
#pragma unroll
    for (int e = 0; e < 8; ++e) acc[e] = 0.f;
#pragma unroll
    for (int j = 0; j < 4; ++j) {
#pragma unroll
      for (int i = 0; i < 4; ++i) {
        const int st = j * 4 + i;
        const float4 wA = rwp4[st * 128 + lane];
        const float4 wB = rwp4[st * 128 + 64 + lane];
        const float xi = (&xv[j].x)[i];
        acc[0] = fmaf(xi, wA.x, acc[0]);
        acc[1] = fmaf(xi, wA.y, acc[1]);
        acc[2] = fmaf(xi, wA.z, acc[2]);
        acc[3] = fmaf(xi, wA.w, acc[3]);
        acc[4] = fmaf(xi, wB.x, acc[4]);
        acc[5] = fmaf(xi, wB.y, acc[5]);
        acc[6] = fmaf(xi, wB.z, acc[6]);
        acc[7] = fmaf(xi, wB.w, acc[7]);
      }
    }
    // butterfly 8 accs -> 1 (expert = bitrev3(lane&7)), then 64-lane sum
#pragma unroll
    for (int i = 0; i < 4; ++i) {
      const float send = (lane & 1) ? acc[i] : acc[i + 4];
      const float recv = __shfl_xor(send, 1);
      acc[i] = ((lane & 1) ? acc[i + 4] : acc[i]) + recv;
    }
#pragma unroll
    for (int i = 0; i < 2; ++i) {
      const float send = (lane & 2) ? acc[i] : acc[i + 2];
      const float recv = __shfl_xor(send, 2);
      acc[i] = ((lane & 2) ? acc[i + 2] : acc[i]) + recv;
    }
    {
      const float send = (lane & 4) ? acc[0] : acc[1];
      const float recv = __shfl_xor(send, 4);
      acc[0] = ((lane & 4) ? acc[1] : acc[0]) + recv;
    }
    float v = acc[0];
    v += __shfl_xor(v, 8); v += __shfl_xor(v, 16); v += __shfl_xor(v, 32);

    const float logit = v + rbe;
    float mx = logit;
    mx = fmaxf(mx, __shfl_xor(mx, 1));
    mx = fmaxf(mx, __shfl_xor(mx, 2));
    mx = fmaxf(mx, __shfl_xor(mx, 4));
    const float ex = expf(logit - mx);
    float sm = ex;
    sm += __shfl_xor(sm, 1); sm += __shfl_xor(sm, 2); sm += __shfl_xor(sm, 4);
    const float p = ex / sm;
    float bv = p; int bi = eln;
#pragma unroll
    for (int mk = 1; mk <= 4; mk <<= 1) {
      const float ov = __shfl_xor(bv, mk);
      const int oi = __shfl_xor(bi, mk);
      if (ov > bv || (ov == bv && oi < bi)) { bv = ov; bi = oi; }
    }
    const int e1 = bi; const float v1 = bv;
    float cv = (eln == e1) ? -1.f : p; int ci = eln;
#pragma unroll
    for (int mk = 1; mk <= 4; mk <<= 1) {
      const float ov = __shfl_xor(cv, mk);
      const int oi = __shfl_xor(ci, mk);
      if (ov > cv || (ov == cv && oi < ci)) { cv = ov; ci = oi; }
    }
    const int e2 = ci; const float v2 = cv;

    if (lane == 0) {
      const float gs = 1.f / (v1 + v2);
      const int li = wave * 4 + tt;
      s_e1[li] = e1; s_g1[li] = v1 * gs;
      s_e2[li] = e2; s_g2[li] = v2 * gs;
      s_pb[li] = e1 * 8 + e2;
    }
    impacc += p;
  }
  if (lane < 8) s_imp[wave][eln] = impacc;
  __syncthreads();
  if (tid < 8)
    imp_part[blockIdx.x * 8 + tid] =
        s_imp[0][tid] + s_imp[1][tid] + s_imp[2][tid] + s_imp[3][tid];

  // per-token records (coalesced, block-contiguous)
  if (tid < 16) {
    pbuf[blockIdx.x * 16 + tid] = s_pb[tid];
    ggbuf[blockIdx.x * 16 + tid] = make_float2(s_g1[tid], s_g2[tid]);
  }
  // transposed histograms: histT[c*1024 + blk], c in [0,80)
  if (tid < 80) {
    int c = 0;
    if (tid < 16) {
      const int k = tid >> 3, e = tid & 7;
#pragma unroll
      for (int j = 0; j < 16; ++j)
        c += ((k ? s_e2[j] : s_e1[j]) == e) ? 1 : 0;
    } else {
      const int b = tid - 16;
#pragma unroll
      for (int j = 0; j < 16; ++j) c += (s_pb[j] == b) ? 1 : 0;
    }
    histT[tid * 1024 + blockIdx.x] = c;
  }
}

// -------- scan+plan+scatter: deterministic, replaces atomics + plan_kernel --
// Phase A: 80 threads prefix-scan histT rows (coalesced int4) -> baseT, totals.
// Phase B: plan tables (as old plan_kernel).
// Phase C: thread t scatters router-block t's 16 tokens using baseT + local rank.
__global__ __launch_bounds__(1024) void scan_scatter_kernel(
    const int* __restrict__ histT, int* __restrict__ baseT,
    const int* __restrict__ pbuf, const float2* __restrict__ ggbuf,
    int* __restrict__ cnt, int* __restrict__ cnt_pair,
    int* __restrict__ totals, int* __restrict__ dplan, int* __restrict__ uplan,
    int* __restrict__ list0, float* __restrict__ gate0,
    int* __restrict__ list1, float* __restrict__ gate1,
    int* __restrict__ pairlist) {
  const int t = threadIdx.x;
  __shared__ int s_tot[80];
  __shared__ int doff[16], uoff[64];
  if (t < 80) {
    const int4* src = (const int4*)(histT + (t << 10));
    int4* dst = (int4*)(baseT + (t << 10));
    int run = 0;
    for (int j = 0; j < 256; ++j) {
      const int4 v = src[j];
      int4 b;
      b.x = run; run += v.x;
      b.y = run; run += v.y;
      b.z = run; run += v.z;
      b.w = run; run += v.w;
      dst[j] = b;
    }
    s_tot[t] = run;
    if (t < 16) cnt[t * 32] = run;
    else        cnt_pair[(t - 16) * 32] = run;
  }
  __syncthreads();
  if (t == 0) {
    int a = 0;
    for (int y = 0; y < 16; ++y) { doff[y] = a; a += (s_tot[y] + 63) >> 6; }
    totals[0] = a;
    a = 0;
    for (int b = 0; b < 64; ++b) { uoff[b] = a; a += (s_tot[16 + b] + 127) >> 7; }
    totals[1] = a;
  }
  __syncthreads();
  if (t < 16) {
    const int n = (s_tot[t] + 63) >> 6;
    for (int i = 0; i < n; ++i) dplan[doff[t] + i] = (t << 16) | i;
  }
  if (t < 64) {
    const int n = (s_tot[16 + t] + 127) >> 7;
    for (int i = 0; i < n; ++i) uplan[uoff[t] + i] = (t << 16) | i;
  }
  // Phase C: scatter (1024 threads, one router block each)
  int pbs[16];
  float g1v[16], g2v[16];
  {
    const int4* ps = (const int4*)(pbuf + (t << 4));
#pragma unroll
    for (int j = 0; j < 4; ++j) {
      const int4 v = ps[j];
      pbs[4 * j + 0] = v.x; pbs[4 * j + 1] = v.y;
      pbs[4 * j + 2] = v.z; pbs[4 * j + 3] = v.w;
    }
    const float4* gp = (const float4*)(ggbuf + (t << 4));
#pragma unroll
    for (int j = 0; j < 8; ++j) {
      const float4 v = gp[j];
      g1v[2 * j]     = v.x; g2v[2 * j]     = v.y;
      g1v[2 * j + 1] = v.z; g2v[2 * j + 1] = v.w;
    }
  }
#pragma unroll
  for (int i = 0; i < 16; ++i) {
    const int pbv = pbs[i];
    const int e1 = pbv >> 3, e2 = pbv & 7;
    int r0 = 0, r1 = 0, rp = 0;
#pragma unroll
    for (int j = 0; j < i; ++j) {
      const int q = pbs[j];
      r0 += ((q >> 3) == e1) ? 1 : 0;
      r1 += ((q & 7) == e2) ? 1 : 0;
      rp += (q == pbv) ? 1 : 0;
    }
    const int token = (t << 4) + i;
    const int s0 = baseT[(e1 << 10) + t] + r0;
    list0[e1 * CAP + s0] = token;
    gate0[e1 * CAP + s0] = g1v[i];
    const int s1 = baseT[((8 + e2) << 10) + t] + r1;
    list1[e2 * CAP + s1] = token;
    gate1[e2 * CAP + s1] = g2v[i];
    const int sp = baseT[((16 + pbv) << 10) + t] + rp;
    pairlist[pbv * CAP + sp] = token;
  }
}

// ---------------- down: H[k][tok] = GELU(x@Wd_e)*gate, 64-token tiles -------
__global__ __launch_bounds__(256) void down_kernel(
    const ushort* __restrict__ xb, const ushort* __restrict__ wdt,
    const int* __restrict__ cnt,
    const int* __restrict__ list0, const float* __restrict__ gate0,
    const int* __restrict__ list1, const float* __restrict__ gate1,
    const int* __restrict__ dplan, const int* __restrict__ totals,
    ushort* __restrict__ Hbuf) {
  if (blockIdx.x >= totals[0]) return;
  const int ent = dplan[blockIdx.x];
  const int y = ent >> 16, tile = ent & 0xffff;
  const int k = y >> 3, e = y & 7;
  const int n = cnt[y * 32];
  const int start = tile * 64;
  const int* list = k ? list1 : list0;
  const float* gate = k ? gate1 : gate0;

  __shared__ ushort As[64 * 64];
  __shared__ ushort Bs[64 * 64];
  __shared__ ushort Hs[64 * 64];
  __shared__ int toks[64];
  __shared__ float gs[64];

  const int tid = threadIdx.x;
  const int lane = tid & 63;
  const int wave = tid >> 6;
  const int wr = wave >> 1, wc = wave & 1;

  if (tid < 64) {
    int tk = -1; float g = 0.f;
    if (start + tid < n) {
      tk = list[e * CAP + start + tid];
      g = gate[e * CAP + start + tid];
    }
    toks[tid] = tk; gs[tid] = g;
  }

  f32x4 acc[2][2];
#pragma unroll
  for (int m = 0; m < 2; ++m)
#pragma unroll
    for (int nn = 0; nn < 2; ++nn) acc[m][nn] = (f32x4){0.f, 0.f, 0.f, 0.f};

  for (int s = 0; s < CDIM / 64; ++s) {
    const int k0 = s * 64;
    __syncthreads();
#pragma unroll
    for (int i = 0; i < 2; ++i) {
      const int sc = tid + i * 256;
      const int row = sc >> 3;
      const int c8 = (sc & 7) * 8;
      const int tk = toks[row];
      const int tkc = tk < 0 ? 0 : tk;
      const ushort8 v = *(const ushort8*)(xb + (size_t)tkc * CDIM + k0 + c8);
      *(ushort8*)&As[row * 64 + (c8 ^ ((row & 7) << 3))] = v;
    }
    {
      const int r = tid & 63;
      const int kq = (tid >> 6) * 16;
      const ushort* src = wdt + (((size_t)e * 64 + r) << 10) + k0 + kq;
      const ushort8 w0 = *(const ushort8*)(src);
      const ushort8 w1 = *(const ushort8*)(src + 8);
      *(ushort8*)&Bs[r * 64 + ((kq + 0) ^ ((r & 7) << 3))] = w0;
      *(ushort8*)&Bs[r * 64 + ((kq + 8) ^ ((r & 7) << 3))] = w1;
    }
    __syncthreads();
#pragma unroll
    for (int kk = 0; kk < 64; kk += 32) {
      const int kb = kk + (lane >> 4) * 8;
      bf16x8 a[2], b[2];
#pragma unroll
      for (int m = 0; m < 2; ++m) {
        const int row = wr * 32 + m * 16 + (lane & 15);
        a[m] = *(const bf16x8*)&As[row * 64 + (kb ^ ((row & 7) << 3))];
      }
#pragma unroll
      for (int nn = 0; nn < 2; ++nn) {
        const int r = wc * 32 + nn * 16 + (lane & 15);
        b[nn] = *(const bf16x8*)&Bs[r * 64 + (kb ^ ((r & 7) << 3))];
      }
#pragma unroll
      for (int m = 0; m < 2; ++m)
#pragma unroll
        for (int nn = 0; nn < 2; ++nn)
          acc[m][nn] = __builtin_amdgcn_mfma_f32_16x16x32_bf16(a[m], b[nn], acc[m][nn], 0, 0, 0);
    }
  }
  // GELU * gate -> Hs (swizzled)
#pragma unroll
  for (int m = 0; m < 2; ++m)
#pragma unroll
    for (int nn = 0; nn < 2; ++nn)
#pragma unroll
      for (int q = 0; q < 4; ++q) {
        const int slot = wr * 32 + m * 16 + (lane >> 4) * 4 + q;
        const int r = wc * 32 + nn * 16 + (lane & 15);
        const float v = acc[m][nn][q];
        const float ge = 0.5f * v * (1.f + erff(v * 0.70710678118654752f));
        Hs[slot * 64 + (r ^ ((slot & 7) << 3))] = f2bf(ge * gs[slot]);
      }
  __syncthreads();
  // Hs -> Hbuf[(k<<14)+tok][64] (linear rows)
  {
    const int row = tid >> 2, part = tid & 3;
    const int tk = toks[row];
    if (tk >= 0) {
      ushort* dst = Hbuf + ((size_t)((k << 14) + tk)) * 64 + part * 16;
      const int c0 = part * 16;
      *(ushort8*)(dst)     = *(const ushort8*)&Hs[row * 64 + ((c0    ) ^ ((row & 7) << 3))];
      *(ushort8*)(dst + 8) = *(const ushort8*)&Hs[row * 64 + ((c0 + 8) ^ ((row & 7) << 3))];
    }
  }
}

// ---------------- up: out[t] = H0[t]@Wu_ea + H1[t]@Wu_eb (pair buckets) -----
__global__ __launch_bounds__(256) void up_kernel(
    const ushort* __restrict__ Hbuf, const ushort* __restrict__ wut,
    const int* __restrict__ cnt_pair, const int* __restrict__ pairlist,
    const int* __restrict__ uplan, const int* __restrict__ totals,
    float* __restrict__ out) {
  if (blockIdx.x >= totals[1]) return;
  const int ent = uplan[blockIdx.x];
  const int b = ent >> 16, tile = ent & 0xffff;
  const int ea = b >> 3, eb = b & 7;
  const int n = cnt_pair[b * 32];
  const int start = tile * 128;
  const int n0 = blockIdx.y * 128;

  __shared__ ushort A0[128 * 64];
  __shared__ ushort A1[128 * 64];
  __shared__ ushort Bx[128 * 64];
  __shared__ int toks[128];

  const int tid = threadIdx.x;
  const int lane = tid & 63;
  const int wave = tid >> 6;
  const int wr = wave >> 1, wc = wave & 1;

  if (tid < 128) {
    int tk = -1;
    if (start + tid < n) tk = pairlist[b * CAP + start + tid];
    toks[tid] = tk;
  }
  __syncthreads();
  // gather H0,H1 rows
#pragma unroll
  for (int i = 0; i < 4; ++i) {
    const int sc = tid + i * 256;
    const int row = sc >> 3;
    const int c8 = (sc & 7) * 8;
    const int tk = toks[row];
    const int tkc = tk < 0 ? 0 : tk;
    const ushort8 v0 = *(const ushort8*)(Hbuf + (size_t)tkc * 64 + c8);
    const ushort8 v1 = *(const ushort8*)(Hbuf + ((size_t)TOKS + tkc) * 64 + c8);
    *(ushort8*)&A0[row * 64 + (c8 ^ ((row & 7) << 3))] = v0;
    *(ushort8*)&A1[row * 64 + (c8 ^ ((row & 7) << 3))] = v1;
  }
  // stage Wu_ea chunk
  {
    const int nn = tid & 127;
    const int rq = (tid >> 7) * 32;
    const ushort* src = wut + (((size_t)ea * 1024 + n0 + nn) << 6) + rq;
#pragma unroll
    for (int j = 0; j < 4; ++j)
      *(ushort8*)&Bx[nn * 64 + ((rq + 8 * j) ^ ((nn & 7) << 3))] =
          *(const ushort8*)(src + 8 * j);
  }
  __syncthreads();

  f32x4 uac[4][4];
#pragma unroll
  for (int m = 0; m < 4; ++m)
#pragma unroll
    for (int nn = 0; nn < 4; ++nn) uac[m][nn] = (f32x4){0.f, 0.f, 0.f, 0.f};

  // pass A: H0 @ Wu_ea
#pragma unroll
  for (int kk = 0; kk < 64; kk += 32) {
    const int kb = kk + (lane >> 4) * 8;
    bf16x8 a[4], bb[4];
#pragma unroll
    for (int m = 0; m < 4; ++m) {
      const int row = wr * 64 + m * 16 + (lane & 15);
      a[m] = *(const bf16x8*)&A0[row * 64 + (kb ^ ((row & 7) << 3))];
    }
#pragma unroll
    for (int nn = 0; nn < 4; ++nn) {
      const int col = wc * 64 + nn * 16 + (lane & 15);
      bb[nn] = *(const bf16x8*)&Bx[col * 64 + (kb ^ ((col & 7) << 3))];
    }
#pragma unroll
    for (int m = 0; m < 4; ++m)
#pragma unroll
      for (int nn = 0; nn < 4; ++nn)
        uac[m][nn] = __builtin_amdgcn_mfma_f32_16x16x32_bf16(a[m], bb[nn], uac[m][nn], 0, 0, 0);
  }
  __syncthreads();
  // restage Bx with Wu_eb chunk
  {
    const int nn = tid & 127;
    const int rq = (tid >> 7) * 32;
    const ushort* src = wut + (((size_t)eb * 1024 + n0 + nn) << 6) + rq;
#pragma unroll
    for (int j = 0; j < 4; ++j)
      *(ushort8*)&Bx[nn * 64 + ((rq + 8 * j) ^ ((nn & 7) << 3))] =
          *(const ushort8*)(src + 8 * j);
  }
  __syncthreads();
  // pass B: H1 @ Wu_eb
#pragma unroll
  for (int kk = 0; kk < 64; kk += 32) {
    const int kb = kk + (lane >> 4) * 8;
    bf16x8 a[4], bb[4];
#pragma unroll
    for (int m = 0; m < 4; ++m) {
      const int row = wr * 64 + m * 16 + (lane & 15);
      a[m] = *(const bf16x8*)&A1[row * 64 + (kb ^ ((row & 7) << 3))];
    }
#pragma unroll
    for (int nn = 0; nn < 4; ++nn) {
      const int col = wc * 64 + nn * 16 + (lane & 15);
      bb[nn] = *(const bf16x8*)&Bx[col * 64 + (kb ^ ((col & 7) << 3))];
    }
#pragma unroll
    for (int m = 0; m < 4; ++m)
#pragma unroll
      for (int nn = 0; nn < 4; ++nn)
        uac[m][nn] = __builtin_amdgcn_mfma_f32_16x16x32_bf16(a[m], bb[nn], uac[m][nn], 0, 0, 0);
  }
  // single store (each token row owned by exactly one bucket)
#pragma unroll
  for (int m = 0; m < 4; ++m)
#pragma unroll
    for (int q = 0; q < 4; ++q) {
      const int slot = wr * 64 + m * 16 + (lane >> 4) * 4 + q;
      const int tk = toks[slot];
      if (tk < 0) continue;
      float* orow = out + (size_t)tk * CDIM + n0 + wc * 64 + (lane & 15);
#pragma unroll
      for (int nn = 0; nn < 4; ++nn) orow[nn * 16] = uac[m][nn][q];
    }
}

// ---------------- aux: deterministic reduce of per-block importance --------
__global__ __launch_bounds__(256) void aux_kernel(
    const int* __restrict__ cnt, const float* __restrict__ imp_part,
    float* __restrict__ out_aux) {
  __shared__ float red[256];
  __shared__ float tot[NEXP];
  const int t = threadIdx.x;
  const int e = t & 7, b0 = t >> 3;
  float s = 0.f;
  for (int j = 0; j < NBLK_R / 32; ++j)
    s += imp_part[(b0 + 32 * j) * 8 + e];
  red[t] = s;
  __syncthreads();
  if (t < 8) {
    float tt = 0.f;
    for (int w = 0; w < 32; ++w) tt += red[w * 8 + t];
    tot[t] = tt;
  }
  __syncthreads();
  if (t == 0) {
    float a = 0.f;
#pragma unroll
    for (int ee = 0; ee < NEXP; ++ee)
      a += (tot[ee] / (float)TOKS) *
           ((float)(cnt[ee * 32] + cnt[(NEXP + ee) * 32]) / (float)(2 * TOKS));
    out_aux[0] = 0.001f * 8.f * a;
  }
}

extern "C" void kernel_launch(void* const* d_in, const int* in_sizes, int n_in,
                              void* d_out, int out_size, void* d_ws, size_t ws_size,
                              hipStream_t stream) {
  const float* x   = (const float*)d_in[0];
  const float* rw  = (const float*)d_in[1];
  const float* rb  = (const float*)d_in[2];
  const float* Wd  = (const float*)d_in[3];
  const float* Wu  = (const float*)d_in[4];
  const int* key_id = (const int*)d_in[5];
  float* out = (float*)d_out;

  char* ws = (char*)d_ws;
  int*    cnt      = (int*)ws;                    // 2 KB  (16 x 128B)
  int*    cnt_pair = (int*)(ws + 2048);           // 8 KB  (64 x 128B)
  int*    totals   = (int*)(ws + 10240);          // 8 B
  float*  imp_part = (float*)(ws + 16384);        // 32 KB
  int*    dplan    = (int*)(ws + 49152);          // ~2 KB
  int*    uplan    = (int*)(ws + 53248);          // ~1 KB
  int*    list0    = (int*)(ws + 65536);          // 512 KB
  float*  gate0    = (float*)(ws + 65536 + 524288);
  int*    list1    = (int*)(ws + 65536 + 1048576);
  float*  gate1    = (float*)(ws + 65536 + 1572864);
  ushort* wdt      = (ushort*)(ws + 2162688);     // 1 MB
  ushort* wut      = (ushort*)(ws + 3211264);     // 1 MB
  ushort* xb       = (ushort*)(ws + 4259840);     // 32 MB -> 37814272
  float*  rw_p     = (float*)(ws + 37814272);     // 32 KB -> 37847040
  int*    pairlist = (int*)(ws + 37847040);       // 4 MB  -> 42041344
  ushort* Hbuf     = (ushort*)(ws + 42041344);    // 4 MB  -> 46235648

  // Router scratch ALIASES the Hbuf region: it is consumed by
  // scan_scatter_kernel before down_kernel overwrites Hbuf. ~0.85 MB.
  int*    histT = (int*)(ws + 42041344);                // 320 KB (80 x 1024 int)
  int*    baseT = (int*)(ws + 42041344 + 327680);       // 320 KB
  int*    pbuf  = (int*)(ws + 42041344 + 655360);       // 64 KB  (16384 int)
  float2* ggbuf = (float2*)(ws + 42041344 + 720896);    // 128 KB (16384 float2)

  convert_kernel<<<1032, 256, 0, stream>>>(Wd, Wu, rw, key_id, wdt, wut, rw_p);
  router_kernel<<<NBLK_R, 256, 0, stream>>>(x, rw_p, rb, key_id, imp_part,
                                            pbuf, ggbuf, histT, xb);
  scan_scatter_kernel<<<1, 1024, 0, stream>>>(histT, baseT, pbuf, ggbuf,
                                              cnt, cnt_pair, totals, dplan, uplan,
                                              list0, gate0, list1, gate1, pairlist);
  down_kernel<<<DT_MAX, 256, 0, stream>>>(xb, wdt, cnt, list0, gate0,
                                          list1, gate1, dplan, totals, Hbuf);
  up_kernel<<<dim3(UT_MAX, CDIM / 128), 256, 0, stream>>>(
      Hbuf, wut, cnt_pair, pairlist, uplan, totals, out);
  aux_kernel<<<1, 256, 0, stream>>>(cnt, imp_part, out + (size_t)TOKS * CDIM);
}

// Round 2
// 89.376 us; speedup vs baseline: 1.8614x; 1.8614x over previous
//
#include <hip/hip_runtime.h>
#include <hip/hip_bf16.h>
#include <math.h>

#define TOKS 16384
#define CDIM 1024
#define NEXP 8
#define RDIM 64
#define CAP  TOKS
#define NBLK_R 1024   // router blocks (16 tokens each)
#define DT_MAX 528    // max down tiles: 2*(16384/64 + 8)
#define UT_MAX 192    // max up tiles: 16384/128 + 64

using f32x4   = __attribute__((ext_vector_type(4))) float;
using bf16x8  = __attribute__((ext_vector_type(8))) short;
using ushort8 = __attribute__((ext_vector_type(8))) unsigned short;

__device__ __forceinline__ ushort f2bf(float f) {
  unsigned u = __builtin_bit_cast(unsigned, f);
  u += 0x7fffu + ((u >> 16) & 1u);   // round-to-nearest-even
  return (ushort)(u >> 16);
}

// ---- pre-pass: rw permute (router-coalesced), Wd->wdt[e][r][k], Wu->wut[e][c][r]
__global__ __launch_bounds__(256) void convert_kernel(
    const float* __restrict__ Wd, const float* __restrict__ Wu,
    const float* __restrict__ rw_all, const int* __restrict__ key_id,
    ushort* __restrict__ wdt, ushort* __restrict__ wut,
    float* __restrict__ rw_p) {
  const int t = blockIdx.x * 256 + threadIdx.x;
  if (t < 2048) {              // rw_p: one float4 per thread
    const int st = t >> 7, rem = t & 127;
    const int h = rem >> 6, l = rem & 63;
    const int C = (st >> 2) * 256 + l * 4 + (st & 3);
    const float4 v = *(const float4*)(rw_all + (size_t)key_id[0] * CDIM * NEXP
                                      + C * 8 + h * 4);
    ((float4*)rw_p)[t] = v;
  } else if (t < 133120) {     // Wd: (e, r, k4)
    const int u = t - 2048;
    const int k4 = u & 255, r = (u >> 8) & 63, e = u >> 14;
    ushort4 h;
    h.x = f2bf(Wd[(size_t)(e * 1024 + k4 * 4 + 0) * 64 + r]);
    h.y = f2bf(Wd[(size_t)(e * 1024 + k4 * 4 + 1) * 64 + r]);
    h.z = f2bf(Wd[(size_t)(e * 1024 + k4 * 4 + 2) * 64 + r]);
    h.w = f2bf(Wd[(size_t)(e * 1024 + k4 * 4 + 3) * 64 + r]);
    ((ushort4*)wdt)[(e * 64 + r) * 256 + k4] = h;
  } else {                     // Wu: (e, c, r4)
    const int u = t - 133120;
    const int r4 = u & 15, c = (u >> 4) & 1023, e = u >> 14;
    ushort4 h;
    h.x = f2bf(Wu[(size_t)(e * 64 + r4 * 4 + 0) * 1024 + c]);
    h.y = f2bf(Wu[(size_t)(e * 64 + r4 * 4 + 1) * 1024 + c]);
    h.z = f2bf(Wu[(size_t)(e * 64 + r4 * 4 + 2) * 1024 + c]);
    h.w = f2bf(Wu[(size_t)(e * 64 + r4 * 4 + 3) * 1024 + c]);
    ((ushort4*)wut)[(e * 1024 + c) * 16 + r4] = h;
  }
}

// ---------------- router: wave = token; NO global atomics ------------------
// Writes per-token records (pbuf/ggbuf) + transposed per-block histograms
// histT[c][blk] for 80 counters (16 (k,e) + 64 pairs). Slot assignment is
// deferred to the distributed scan/scatter kernels.
__global__ __launch_bounds__(256) void router_kernel(
    const float* __restrict__ x, const float* __restrict__ rw_p,
    const float* __restrict__ rb_all, const int* __restrict__ key_id,
    float* __restrict__ imp_part,
    int* __restrict__ pbuf, float2* __restrict__ ggbuf,
    int* __restrict__ histT, ushort* __restrict__ xb) {
  __shared__ float s_imp[4][NEXP];
  __shared__ int   s_e1[16], s_e2[16], s_pb[16];
  __shared__ float s_g1[16], s_g2[16];
  const int tid = threadIdx.x;
  const int lane = tid & 63;
  const int wave = tid >> 6;
  const int kid = key_id[0];
  const float4* rwp4 = (const float4*)rw_p;
  const float* rb = rb_all + (size_t)kid * NEXP;
  const int eln = ((lane & 1) << 2) | (lane & 2) | ((lane >> 2) & 1);
  const float rbe = rb[eln];
  float impacc = 0.f;

  const int wg = blockIdx.x * 4 + wave;
#pragma unroll 1
  for (int tt = 0; tt < 4; ++tt) {
    const int token = wg * 4 + tt;
    const float* xr = x + (size_t)token * CDIM + lane * 4;
    float4 xv[4];
#pragma unroll
    for (int j = 0; j < 4; ++j) xv[j] = *(const float4*)(xr + j * 256);
    ushort* xo = xb + (size_t)token * CDIM + lane * 4;
#pragma unroll
    for (int j = 0; j < 4; ++j) {
      ushort4 h;
      h.x = f2bf(xv[j].x); h.y = f2bf(xv[j].y);
      h.z = f2bf(xv[j].z); h.w = f2bf(xv[j].w);
      *(ushort4*)(xo + j * 256) = h;
    }
    float acc[8];
#pragma unroll
    for (int e = 0; e < 8; ++e) acc[e] = 0.f;
#pragma unroll
    for (int j = 0; j < 4; ++j) {
#pragma unroll
      for (int i = 0; i < 4; ++i) {
        const int st = j * 4 + i;
        const float4 wA = rwp4[st * 128 + lane];
        const float4 wB = rwp4[st * 128 + 64 + lane];
        const float xi = (&xv[j].x)[i];
        acc[0] = fmaf(xi, wA.x, acc[0]);
        acc[1] = fmaf(xi, wA.y, acc[1]);
        acc[2] = fmaf(xi, wA.z, acc[2]);
        acc[3] = fmaf(xi, wA.w, acc[3]);
        acc[4] = fmaf(xi, wB.x, acc[4]);
        acc[5] = fmaf(xi, wB.y, acc[5]);
        acc[6] = fmaf(xi, wB.z, acc[6]);
        acc[7] = fmaf(xi, wB.w, acc[7]);
      }
    }
    // butterfly 8 accs -> 1 (expert = bitrev3(lane&7)), then 64-lane sum
#pragma unroll
    for (int i = 0; i < 4; ++i) {
      const float send = (lane & 1) ? acc[i] : acc[i + 4];
      const float recv = __shfl_xor(send, 1);
      acc[i] = ((lane & 1) ? acc[i + 4] : acc[i]) + recv;
    }
#pragma unroll
    for (int i = 0; i < 2; ++i) {
      const float send = (lane & 2) ? acc[i] : acc[i + 2];
      const float recv = __shfl_xor(send, 2);
      acc[i] = ((lane & 2) ? acc[i + 2] : acc[i]) + recv;
    }
    {
      const float send = (lane & 4) ? acc[0] : acc[1];
      const float recv = __shfl_xor(send, 4);
      acc[0] = ((lane & 4) ? acc[1] : acc[0]) + recv;
    }
    float v = acc[0];
    v += __shfl_xor(v, 8); v += __shfl_xor(v, 16); v += __shfl_xor(v, 32);

    const float logit = v + rbe;
    float mx = logit;
    mx = fmaxf(mx, __shfl_xor(mx, 1));
    mx = fmaxf(mx, __shfl_xor(mx, 2));
    mx = fmaxf(mx, __shfl_xor(mx, 4));
    const float ex = expf(logit - mx);
    float sm = ex;
    sm += __shfl_xor(sm, 1); sm += __shfl_xor(sm, 2); sm += __shfl_xor(sm, 4);
    const float p = ex / sm;
    float bv = p; int bi = eln;
#pragma unroll
    for (int mk = 1; mk <= 4; mk <<= 1) {
      const float ov = __shfl_xor(bv, mk);
      const int oi = __shfl_xor(bi, mk);
      if (ov > bv || (ov == bv && oi < bi)) { bv = ov; bi = oi; }
    }
    const int e1 = bi; const float v1 = bv;
    float cv = (eln == e1) ? -1.f : p; int ci = eln;
#pragma unroll
    for (int mk = 1; mk <= 4; mk <<= 1) {
      const float ov = __shfl_xor(cv, mk);
      const int oi = __shfl_xor(ci, mk);
      if (ov > cv || (ov == cv && oi < ci)) { cv = ov; ci = oi; }
    }
    const int e2 = ci; const float v2 = cv;

    if (lane == 0) {
      const float gs = 1.f / (v1 + v2);
      const int li = wave * 4 + tt;
      s_e1[li] = e1; s_g1[li] = v1 * gs;
      s_e2[li] = e2; s_g2[li] = v2 * gs;
      s_pb[li] = e1 * 8 + e2;
    }
    impacc += p;
  }
  if (lane < 8) s_imp[wave][eln] = impacc;
  __syncthreads();
  if (tid < 8)
    imp_part[blockIdx.x * 8 + tid] =
        s_imp[0][tid] + s_imp[1][tid] + s_imp[2][tid] + s_imp[3][tid];

  // per-token records (coalesced, block-contiguous)
  if (tid < 16) {
    pbuf[blockIdx.x * 16 + tid] = s_pb[tid];
    ggbuf[blockIdx.x * 16 + tid] = make_float2(s_g1[tid], s_g2[tid]);
  }
  // transposed histograms: histT[c*1024 + blk], c in [0,80)
  if (tid < 80) {
    int c = 0;
    if (tid < 16) {
      const int k = tid >> 3, e = tid & 7;
#pragma unroll
      for (int j = 0; j < 16; ++j)
        c += ((k ? s_e2[j] : s_e1[j]) == e) ? 1 : 0;
    } else {
      const int b = tid - 16;
#pragma unroll
      for (int j = 0; j < 16; ++j) c += (s_pb[j] == b) ? 1 : 0;
    }
    histT[tid * 1024 + blockIdx.x] = c;
  }
}

// -------- scan: one block per counter, parallel prefix over 1024 blocks ----
__global__ __launch_bounds__(256) void scan_kernel(
    const int* __restrict__ histT, int* __restrict__ baseT,
    int* __restrict__ cnt, int* __restrict__ cnt_pair) {
  __shared__ int ls[256];
  const int c = blockIdx.x;
  const int t = threadIdx.x;
  const int4 v = ((const int4*)(histT + (c << 10)))[t];
  const int s = v.x + v.y + v.z + v.w;
  ls[t] = s;
  __syncthreads();
  // Hillis-Steele inclusive scan over 256 partials
#pragma unroll
  for (int off = 1; off < 256; off <<= 1) {
    const int add = (t >= off) ? ls[t - off] : 0;
    __syncthreads();
    ls[t] += add;
    __syncthreads();
  }
  const int incl = ls[t];
  const int excl = incl - s;
  int4 b;
  b.x = excl;
  b.y = excl + v.x;
  b.z = excl + v.x + v.y;
  b.w = excl + v.x + v.y + v.z;
  ((int4*)(baseT + (c << 10)))[t] = b;
  if (t == 255) {
    if (c < 16) cnt[c * 32] = incl;
    else        cnt_pair[(c - 16) * 32] = incl;
  }
}

// ---------------- plan: compact tile tables for down/up grids ---------------
__global__ void plan_kernel(const int* __restrict__ cnt,
                            const int* __restrict__ cnt_pair,
                            int* __restrict__ dplan, int* __restrict__ uplan,
                            int* __restrict__ totals) {
  __shared__ int doff[16], uoff[64];
  if (threadIdx.x == 0) {
    int t = 0;
    for (int y = 0; y < 16; ++y) { doff[y] = t; t += (cnt[y * 32] + 63) >> 6; }
    totals[0] = t;
    t = 0;
    for (int b = 0; b < 64; ++b) { uoff[b] = t; t += (cnt_pair[b * 32] + 127) >> 7; }
    totals[1] = t;
  }
  __syncthreads();
  const int tid = threadIdx.x;
  if (tid < 16) {
    const int n = (cnt[tid * 32] + 63) >> 6;
    for (int i = 0; i < n; ++i) dplan[doff[tid] + i] = (tid << 16) | i;
  }
  const int n = (cnt_pair[tid * 32] + 127) >> 7;
  for (int i = 0; i < n; ++i) uplan[uoff[tid] + i] = (tid << 16) | i;
}

// -------- scatter: one wave per router block, ranks via shfl ---------------
__global__ __launch_bounds__(256) void scatter_kernel(
    const int* __restrict__ baseT,
    const int* __restrict__ pbuf, const float2* __restrict__ ggbuf,
    int* __restrict__ list0, float* __restrict__ gate0,
    int* __restrict__ list1, float* __restrict__ gate1,
    int* __restrict__ pairlist) {
  const int tid = threadIdx.x;
  const int lane = tid & 63;
  const int wave = tid >> 6;
  const int rb = blockIdx.x * 4 + wave;   // router block, 0..1023
  const int i = lane;                     // token index within block (0..15)
  int pb = 0;
  float2 gg = make_float2(0.f, 0.f);
  if (lane < 16) {
    pb = pbuf[rb * 16 + lane];
    gg = ggbuf[rb * 16 + lane];
  }
  const int e1 = pb >> 3, e2 = pb & 7;
  int r0 = 0, r1 = 0, rp = 0;
#pragma unroll
  for (int j = 0; j < 15; ++j) {
    const int q = __shfl(pb, j);
    if (j < i) {
      r0 += ((q >> 3) == e1) ? 1 : 0;
      r1 += ((q & 7) == e2) ? 1 : 0;
      rp += (q == pb) ? 1 : 0;
    }
  }
  if (lane < 16) {
    const int token = rb * 16 + i;
    const int s0 = baseT[(e1 << 10) + rb] + r0;
    list0[e1 * CAP + s0] = token;
    gate0[e1 * CAP + s0] = gg.x;
    const int s1 = baseT[((8 + e2) << 10) + rb] + r1;
    list1[e2 * CAP + s1] = token;
    gate1[e2 * CAP + s1] = gg.y;
    const int sp = baseT[((16 + pb) << 10) + rb] + rp;
    pairlist[pb * CAP + sp] = token;
  }
}

// ---------------- down: H[k][tok] = GELU(x@Wd_e)*gate, 64-token tiles -------
__global__ __launch_bounds__(256) void down_kernel(
    const ushort* __restrict__ xb, const ushort* __restrict__ wdt,
    const int* __restrict__ cnt,
    const int* __restrict__ list0, const float* __restrict__ gate0,
    const int* __restrict__ list1, const float* __restrict__ gate1,
    const int* __restrict__ dplan, const int* __restrict__ totals,
    ushort* __restrict__ Hbuf) {
  if (blockIdx.x >= totals[0]) return;
  const int ent = dplan[blockIdx.x];
  const int y = ent >> 16, tile = ent & 0xffff;
  const int k = y >> 3, e = y & 7;
  const int n = cnt[y * 32];
  const int start = tile * 64;
  const int* list = k ? list1 : list0;
  const float* gate = k ? gate1 : gate0;

  __shared__ ushort As[64 * 64];
  __shared__ ushort Bs[64 * 64];
  __shared__ ushort Hs[64 * 64];
  __shared__ int toks[64];
  __shared__ float gs[64];

  const int tid = threadIdx.x;
  const int lane = tid & 63;
  const int wave = tid >> 6;
  const int wr = wave >> 1, wc = wave & 1;

  if (tid < 64) {
    int tk = -1; float g = 0.f;
    if (start + tid < n) {
      tk = list[e * CAP + start + tid];
      g = gate[e * CAP + start + tid];
    }
    toks[tid] = tk; gs[tid] = g;
  }

  f32x4 acc[2][2];
#pragma unroll
  for (int m = 0; m < 2; ++m)
#pragma unroll
    for (int nn = 0; nn < 2; ++nn) acc[m][nn] = (f32x4){0.f, 0.f, 0.f, 0.f};

  for (int s = 0; s < CDIM / 64; ++s) {
    const int k0 = s * 64;
    __syncthreads();
#pragma unroll
    for (int i = 0; i < 2; ++i) {
      const int sc = tid + i * 256;
      const int row = sc >> 3;
      const int c8 = (sc & 7) * 8;
      const int tk = toks[row];
      const int tkc = tk < 0 ? 0 : tk;
      const ushort8 v = *(const ushort8*)(xb + (size_t)tkc * CDIM + k0 + c8);
      *(ushort8*)&As[row * 64 + (c8 ^ ((row & 7) << 3))] = v;
    }
    {
      const int r = tid & 63;
      const int kq = (tid >> 6) * 16;
      const ushort* src = wdt + (((size_t)e * 64 + r) << 10) + k0 + kq;
      const ushort8 w0 = *(const ushort8*)(src);
      const ushort8 w1 = *(const ushort8*)(src + 8);
      *(ushort8*)&Bs[r * 64 + ((kq + 0) ^ ((r & 7) << 3))] = w0;
      *(ushort8*)&Bs[r * 64 + ((kq + 8) ^ ((r & 7) << 3))] = w1;
    }
    __syncthreads();
#pragma unroll
    for (int kk = 0; kk < 64; kk += 32) {
      const int kb = kk + (lane >> 4) * 8;
      bf16x8 a[2], b[2];
#pragma unroll
      for (int m = 0; m < 2; ++m) {
        const int row = wr * 32 + m * 16 + (lane & 15);
        a[m] = *(const bf16x8*)&As[row * 64 + (kb ^ ((row & 7) << 3))];
      }
#pragma unroll
      for (int nn = 0; nn < 2; ++nn) {
        const int r = wc * 32 + nn * 16 + (lane & 15);
        b[nn] = *(const bf16x8*)&Bs[r * 64 + (kb ^ ((r & 7) << 3))];
      }
#pragma unroll
      for (int m = 0; m < 2; ++m)
#pragma unroll
        for (int nn = 0; nn < 2; ++nn)
          acc[m][nn] = __builtin_amdgcn_mfma_f32_16x16x32_bf16(a[m], b[nn], acc[m][nn], 0, 0, 0);
    }
  }
  // GELU * gate -> Hs (swizzled)
#pragma unroll
  for (int m = 0; m < 2; ++m)
#pragma unroll
    for (int nn = 0; nn < 2; ++nn)
#pragma unroll
      for (int q = 0; q < 4; ++q) {
        const int slot = wr * 32 + m * 16 + (lane >> 4) * 4 + q;
        const int r = wc * 32 + nn * 16 + (lane & 15);
        const float v = acc[m][nn][q];
        const float ge = 0.5f * v * (1.f + erff(v * 0.70710678118654752f));
        Hs[slot * 64 + (r ^ ((slot & 7) << 3))] = f2bf(ge * gs[slot]);
      }
  __syncthreads();
  // Hs -> Hbuf[(k<<14)+tok][64] (linear rows)
  {
    const int row = tid >> 2, part = tid & 3;
    const int tk = toks[row];
    if (tk >= 0) {
      ushort* dst = Hbuf + ((size_t)((k << 14) + tk)) * 64 + part * 16;
      const int c0 = part * 16;
      *(ushort8*)(dst)     = *(const ushort8*)&Hs[row * 64 + ((c0    ) ^ ((row & 7) << 3))];
      *(ushort8*)(dst + 8) = *(const ushort8*)&Hs[row * 64 + ((c0 + 8) ^ ((row & 7) << 3))];
    }
  }
}

// ---------------- up: out[t] = H0[t]@Wu_ea + H1[t]@Wu_eb (pair buckets) -----
__global__ __launch_bounds__(256) void up_kernel(
    const ushort* __restrict__ Hbuf, const ushort* __restrict__ wut,
    const int* __restrict__ cnt_pair, const int* __restrict__ pairlist,
    const int* __restrict__ uplan, const int* __restrict__ totals,
    float* __restrict__ out) {
  if (blockIdx.x >= totals[1]) return;
  const int ent = uplan[blockIdx.x];
  const int b = ent >> 16, tile = ent & 0xffff;
  const int ea = b >> 3, eb = b & 7;
  const int n = cnt_pair[b * 32];
  const int start = tile * 128;
  const int n0 = blockIdx.y * 128;

  __shared__ ushort A0[128 * 64];
  __shared__ ushort A1[128 * 64];
  __shared__ ushort Bx[128 * 64];
  __shared__ int toks[128];

  const int tid = threadIdx.x;
  const int lane = tid & 63;
  const int wave = tid >> 6;
  const int wr = wave >> 1, wc = wave & 1;

  if (tid < 128) {
    int tk = -1;
    if (start + tid < n) tk = pairlist[b * CAP + start + tid];
    toks[tid] = tk;
  }
  __syncthreads();
  // gather H0,H1 rows
#pragma unroll
  for (int i = 0; i < 4; ++i) {
    const int sc = tid + i * 256;
    const int row = sc >> 3;
    const int c8 = (sc & 7) * 8;
    const int tk = toks[row];
    const int tkc = tk < 0 ? 0 : tk;
    const ushort8 v0 = *(const ushort8*)(Hbuf + (size_t)tkc * 64 + c8);
    const ushort8 v1 = *(const ushort8*)(Hbuf + ((size_t)TOKS + tkc) * 64 + c8);
    *(ushort8*)&A0[row * 64 + (c8 ^ ((row & 7) << 3))] = v0;
    *(ushort8*)&A1[row * 64 + (c8 ^ ((row & 7) << 3))] = v1;
  }
  // stage Wu_ea chunk
  {
    const int nn = tid & 127;
    const int rq = (tid >> 7) * 32;
    const ushort* src = wut + (((size_t)ea * 1024 + n0 + nn) << 6) + rq;
#pragma unroll
    for (int j = 0; j < 4; ++j)
      *(ushort8*)&Bx[nn * 64 + ((rq + 8 * j) ^ ((nn & 7) << 3))] =
          *(const ushort8*)(src + 8 * j);
  }
  __syncthreads();

  f32x4 uac[4][4];
#pragma unroll
  for (int m = 0; m < 4; ++m)
#pragma unroll
    for (int nn = 0; nn < 4; ++nn) uac[m][nn] = (f32x4){0.f, 0.f, 0.f, 0.f};

  // pass A: H0 @ Wu_ea
#pragma unroll
  for (int kk = 0; kk < 64; kk += 32) {
    const int kb = kk + (lane >> 4) * 8;
    bf16x8 a[4], bb[4];
#pragma unroll
    for (int m = 0; m < 4; ++m) {
      const int row = wr * 64 + m * 16 + (lane & 15);
      a[m] = *(const bf16x8*)&A0[row * 64 + (kb ^ ((row & 7) << 3))];
    }
#pragma unroll
    for (int nn = 0; nn < 4; ++nn) {
      const int col = wc * 64 + nn * 16 + (lane & 15);
      bb[nn] = *(const bf16x8*)&Bx[col * 64 + (kb ^ ((col & 7) << 3))];
    }
#pragma unroll
    for (int m = 0; m < 4; ++m)
#pragma unroll
      for (int nn = 0; nn < 4; ++nn)
        uac[m][nn] = __builtin_amdgcn_mfma_f32_16x16x32_bf16(a[m], bb[nn], uac[m][nn], 0, 0, 0);
  }
  __syncthreads();
  // restage Bx with Wu_eb chunk
  {
    const int nn = tid & 127;
    const int rq = (tid >> 7) * 32;
    const ushort* src = wut + (((size_t)eb * 1024 + n0 + nn) << 6) + rq;
#pragma unroll
    for (int j = 0; j < 4; ++j)
      *(ushort8*)&Bx[nn * 64 + ((rq + 8 * j) ^ ((nn & 7) << 3))] =
          *(const ushort8*)(src + 8 * j);
  }
  __syncthreads();
  // pass B: H1 @ Wu_eb
#pragma unroll
  for (int kk = 0; kk < 64; kk += 32) {
    const int kb = kk + (lane >> 4) * 8;
    bf16x8 a[4], bb[4];
#pragma unroll
    for (int m = 0; m < 4; ++m) {
      const int row = wr * 64 + m * 16 + (lane & 15);
      a[m] = *(const bf16x8*)&A1[row * 64 + (kb ^ ((row & 7) << 3))];
    }
#pragma unroll
    for (int nn = 0; nn < 4; ++nn) {
      const int col = wc * 64 + nn * 16 + (lane & 15);
      bb[nn] = *(const bf16x8*)&Bx[col * 64 + (kb ^ ((col & 7) << 3))];
    }
#pragma unroll
    for (int m = 0; m < 4; ++m)
#pragma unroll
      for (int nn = 0; nn < 4; ++nn)
        uac[m][nn] = __builtin_amdgcn_mfma_f32_16x16x32_bf16(a[m], bb[nn], uac[m][nn], 0, 0, 0);
  }
  // single store (each token row owned by exactly one bucket)
#pragma unroll
  for (int m = 0; m < 4; ++m)
#pragma unroll
    for (int q = 0; q < 4; ++q) {
      const int slot = wr * 64 + m * 16 + (lane >> 4) * 4 + q;
      const int tk = toks[slot];
      if (tk < 0) continue;
      float* orow = out + (size_t)tk * CDIM + n0 + wc * 64 + (lane & 15);
#pragma unroll
      for (int nn = 0; nn < 4; ++nn) orow[nn * 16] = uac[m][nn][q];
    }
}

// ---------------- aux: deterministic reduce of per-block importance --------
__global__ __launch_bounds__(256) void aux_kernel(
    const int* __restrict__ cnt, const float* __restrict__ imp_part,
    float* __restrict__ out_aux) {
  __shared__ float red[256];
  __shared__ float tot[NEXP];
  const int t = threadIdx.x;
  const int e = t & 7, b0 = t >> 3;
  float s = 0.f;
  for (int j = 0; j < NBLK_R / 32; ++j)
    s += imp_part[(b0 + 32 * j) * 8 + e];
  red[t] = s;
  __syncthreads();
  if (t < 8) {
    float tt = 0.f;
    for (int w = 0; w < 32; ++w) tt += red[w * 8 + t];
    tot[t] = tt;
  }
  __syncthreads();
  if (t == 0) {
    float a = 0.f;
#pragma unroll
    for (int ee = 0; ee < NEXP; ++ee)
      a += (tot[ee] / (float)TOKS) *
           ((float)(cnt[ee * 32] + cnt[(NEXP + ee) * 32]) / (float)(2 * TOKS));
    out_aux[0] = 0.001f * 8.f * a;
  }
}

extern "C" void kernel_launch(void* const* d_in, const int* in_sizes, int n_in,
                              void* d_out, int out_size, void* d_ws, size_t ws_size,
                              hipStream_t stream) {
  const float* x   = (const float*)d_in[0];
  const float* rw  = (const float*)d_in[1];
  const float* rb  = (const float*)d_in[2];
  const float* Wd  = (const float*)d_in[3];
  const float* Wu  = (const float*)d_in[4];
  const int* key_id = (const int*)d_in[5];
  float* out = (float*)d_out;

  char* ws = (char*)d_ws;
  int*    cnt      = (int*)ws;                    // 2 KB  (16 x 128B)
  int*    cnt_pair = (int*)(ws + 2048);           // 8 KB  (64 x 128B)
  int*    totals   = (int*)(ws + 10240);          // 8 B
  float*  imp_part = (float*)(ws + 16384);        // 32 KB
  int*    dplan    = (int*)(ws + 49152);          // ~2 KB
  int*    uplan    = (int*)(ws + 53248);          // ~1 KB
  int*    list0    = (int*)(ws + 65536);          // 512 KB
  float*  gate0    = (float*)(ws + 65536 + 524288);
  int*    list1    = (int*)(ws + 65536 + 1048576);
  float*  gate1    = (float*)(ws + 65536 + 1572864);
  ushort* wdt      = (ushort*)(ws + 2162688);     // 1 MB
  ushort* wut      = (ushort*)(ws + 3211264);     // 1 MB
  ushort* xb       = (ushort*)(ws + 4259840);     // 32 MB -> 37814272
  float*  rw_p     = (float*)(ws + 37814272);     // 32 KB -> 37847040
  int*    pairlist = (int*)(ws + 37847040);       // 4 MB  -> 42041344
  ushort* Hbuf     = (ushort*)(ws + 42041344);    // 4 MB  -> 46235648

  // Router scratch ALIASES the Hbuf region: fully consumed by scan/scatter
  // before down_kernel overwrites Hbuf. ~0.85 MB.
  int*    histT = (int*)(ws + 42041344);                // 320 KB (80 x 1024 int)
  int*    baseT = (int*)(ws + 42041344 + 327680);       // 320 KB
  int*    pbuf  = (int*)(ws + 42041344 + 655360);       // 64 KB  (16384 int)
  float2* ggbuf = (float2*)(ws + 42041344 + 720896);    // 128 KB (16384 float2)

  convert_kernel<<<1032, 256, 0, stream>>>(Wd, Wu, rw, key_id, wdt, wut, rw_p);
  router_kernel<<<NBLK_R, 256, 0, stream>>>(x, rw_p, rb, key_id, imp_part,
                                            pbuf, ggbuf, histT, xb);
  scan_kernel<<<80, 256, 0, stream>>>(histT, baseT, cnt, cnt_pair);
  plan_kernel<<<1, 64, 0, stream>>>(cnt, cnt_pair, dplan, uplan, totals);
  scatter_kernel<<<256, 256, 0, stream>>>(baseT, pbuf, ggbuf,
                                          list0, gate0, list1, gate1, pairlist);
  down_kernel<<<DT_MAX, 256, 0, stream>>>(xb, wdt, cnt, list0, gate0,
                                          list1, gate1, dplan, totals, Hbuf);
  up_kernel<<<dim3(UT_MAX, CDIM / 128), 256, 0, stream>>>(
      Hbuf, wut, cnt_pair, pairlist, uplan, totals, out);
  aux_kernel<<<1, 256, 0, stream>>>(cnt, imp_part, out + (size_t)TOKS * CDIM);
}